// Round 9
// baseline (547.644 us; speedup 1.0000x reference)
//
#include <hip/hip_runtime.h>

#define CH 128

typedef _Float16 f16;
typedef _Float16 f16x8 __attribute__((ext_vector_type(8)));
typedef float f32x4 __attribute__((ext_vector_type(4)));

__device__ __forceinline__ f32x4 mfma16(f16x8 a, f16x8 b, f32x4 c) {
    return __builtin_amdgcn_mfma_f32_16x16x32_f16(a, b, c, 0, 0, 0);
}

// ---------------- fused front: hist(+rank) + weight prep (3 layers) + x->f16 cvt ----------------
__global__ __launch_bounds__(256) void k_front(const int* __restrict__ edst, int* __restrict__ counts,
                                               int* __restrict__ erank, int E,
                                               const float* __restrict__ W1a, const float* __restrict__ W2a,
                                               const float* __restrict__ W1b, const float* __restrict__ W2b,
                                               const float* __restrict__ W1c, const float* __restrict__ W2c,
                                               f16* __restrict__ WcT, f16* __restrict__ W2T,
                                               const float* __restrict__ x, f16* __restrict__ act,
                                               int total4, int gHist) {
    int bid = blockIdx.x;
    if (bid < gHist) {
        int e = bid * 256 + threadIdx.x;
        if (e < E) erank[e] = atomicAdd(&counts[edst[e]], 1);   // rank doubles as scatter cursor
    } else if (bid < gHist + 576) {
        int r = bid - gHist;
        int l = r / 192;
        const float* W1 = (l == 0) ? W1a : (l == 1) ? W1b : W1c;
        const float* W2 = (l == 0) ? W2a : (l == 1) ? W2b : W2c;
        f16* wct = WcT + l * 256 * CH;
        f16* w2t = W2T + l * CH * CH;
        int id = (r % 192) * 256 + threadIdx.x;   // 49152 per layer
        if (id < 32768) {
            int n = id >> 7, k = id & 127;
            float v;
            if (n < CH) v = W1[k * CH + n] - W1[(CH + k) * CH + n];
            else        v = W1[(CH + k) * CH + (n - CH)];
            wct[n * CH + k] = (f16)v;
        } else {
            int rr = id - 32768;
            int n = rr >> 7, k = rr & 127;
            w2t[n * CH + k] = (f16)W2[k * CH + n];
        }
    } else {
        int i = (bid - gHist - 576) * 256 + threadIdx.x;
        if (i < total4) {
            float4 v = ((const float4*)x)[i];
            f16 h0 = (f16)v.x, h1 = (f16)v.y, h2 = (f16)v.z, h3 = (f16)v.w;
            short4 s;
            s.x = *(short*)&h0; s.y = *(short*)&h1; s.z = *(short*)&h2; s.w = *(short*)&h3;
            ((short4*)act)[i] = s;
        }
    }
}

// ---------------- CSR scans + scatter ----------------
__global__ __launch_bounds__(256) void k_scan1(const int* __restrict__ counts, int* __restrict__ row_ptr,
                                               int* __restrict__ blockSums, int n) {
    __shared__ int s[256];
    int t = threadIdx.x;
    int i = blockIdx.x * 256 + t;
    s[t] = (i < n) ? counts[i] : 0;
    __syncthreads();
    for (int off = 1; off < 256; off <<= 1) {
        int x = (t >= off) ? s[t - off] : 0;
        __syncthreads();
        s[t] += x;
        __syncthreads();
    }
    if (i < n) row_ptr[i + 1] = s[t];
    if (t == 255) blockSums[blockIdx.x] = s[255];
}

__global__ __launch_bounds__(256) void k_scan2(const int* __restrict__ blockSums, int* __restrict__ blockOff, int nb) {
    __shared__ int s[256];
    int t = threadIdx.x;
    s[t] = (t < nb) ? blockSums[t] : 0;
    __syncthreads();
    for (int off = 1; off < 256; off <<= 1) {
        int x = (t >= off) ? s[t - off] : 0;
        __syncthreads();
        s[t] += x;
        __syncthreads();
    }
    blockOff[t] = (t == 0) ? 0 : s[t - 1];
}

__global__ __launch_bounds__(256) void k_scan3(int* __restrict__ row_ptr, const int* __restrict__ blockOff, int n) {
    int i = blockIdx.x * 256 + threadIdx.x;
    if (i < n) row_ptr[i + 1] += blockOff[blockIdx.x];
    if (blockIdx.x == 0 && threadIdx.x == 0) row_ptr[0] = 0;
}

// atomic-free scatter: pos = row_ptr[dst] + precomputed rank
__global__ __launch_bounds__(256) void k_scatter(const int* __restrict__ src, const int* __restrict__ dst,
                                                 const int* __restrict__ row_ptr, const int* __restrict__ erank,
                                                 int* __restrict__ sed, int E) {
    int e = blockIdx.x * 256 + threadIdx.x;
    if (e < E) {
        int pos = row_ptr[dst[e]] + erank[e];
        sed[pos] = src[e];
    }
}

// ---------------- node GEMM: [P|Q] = act @ WcT^T, P gets +b1. 256 rows/block ----------------
__global__ __launch_bounds__(256) void k_gemm1(const f16* __restrict__ act, const f16* __restrict__ WcT,
                                               const float* __restrict__ b1,
                                               f16* __restrict__ P, f16* __restrict__ Q, int nrows) {
    int t = threadIdx.x;
    int w = t >> 6, lane = t & 63;
    int m = lane & 15, q = lane >> 4;
    int rowbase = blockIdx.x * 256 + w * 64;
    f16x8 a[4][4];   // [row-tile][kk]
#pragma unroll
    for (int rt = 0; rt < 4; ++rt) {
        int rowc = min(rowbase + rt * 16 + m, nrows - 1);
#pragma unroll
        for (int kk = 0; kk < 4; ++kk)
            a[rt][kk] = *(const f16x8*)(act + (size_t)rowc * CH + kk * 32 + q * 8);
    }
#pragma unroll
    for (int nb = 0; nb < 16; ++nb) {
        f16x8 b[4];
#pragma unroll
        for (int kk = 0; kk < 4; ++kk)
            b[kk] = *(const f16x8*)(WcT + (nb * 16 + m) * CH + kk * 32 + q * 8);
        int col = nb * 16 + m;
        float bias = (nb < 8) ? b1[col] : 0.f;
#pragma unroll
        for (int rt = 0; rt < 4; ++rt) {
            f32x4 acc = {0.f, 0.f, 0.f, 0.f};
#pragma unroll
            for (int kk = 0; kk < 4; ++kk) acc = mfma16(a[rt][kk], b[kk], acc);
#pragma unroll
            for (int r = 0; r < 4; ++r) {
                int ro = rowbase + rt * 16 + q * 4 + r;
                if (ro < nrows) {
                    float v = acc[r] + bias;
                    if (nb < 8) P[(size_t)ro * CH + col] = (f16)v;
                    else        Q[(size_t)ro * CH + (col - CH)] = (f16)v;
                }
            }
        }
    }
}

// ---------------- per-pair edge GEMM + register max: 1 wave = 2 consecutive dst nodes ----
// v6: LDS-bound fix. v3 read 32KB of W2 fragments per 16-edge tile (2.29GB/dispatch,
// ~60% of kernel time). Pairing 2 nodes per wave shares each B read across 2 MFMAs and
// pools tiles (pair computes max(T0,T1) shared tiles; clamp-padding duplicates edges,
// harmless under max): B traffic -40%. nb-outer/kk-inner keeps acc at 8 regs; row_ptr
// meta readfirstlane'd to SGPRs; wave-uniform branches. bounds(256,3) — v4/v5 proved
// 4 waves/SIMD spills this state size.
// flags: bit0 relu out, bit1 fp32 final out.
__global__ __launch_bounds__(256, 3)
void k_node(const f16* __restrict__ P, const f16* __restrict__ Q,
            const f16* __restrict__ W2Tg, const float* __restrict__ b2,
            const int* __restrict__ row_ptr, const int* __restrict__ sed,
            f16* __restrict__ act_out, float* __restrict__ final_out,
            int n_nodes, int flags, int nwv) {
    // W2^T in fragment order: chunk cid=(nb*4+kk)*64+lane holds the 16B this lane
    // needs for (nb,kk). ds_read_b128 at lane*16 + imm -> lane-contiguous, conflict-free.
    __shared__ __align__(16) f16 w2lds[8 * 4 * 64 * 8];   // 32 KB

    int t = threadIdx.x;
    int w = t >> 6, lane = t & 63;
    int m = lane & 15, q = lane >> 4;

#pragma unroll
    for (int i = t; i < 2048; i += 256) {
        int nb = i >> 8, rem = i & 255, kk = rem >> 6, ln = rem & 63;
        int mm = ln & 15, qq = ln >> 4;
        *(f16x8*)&w2lds[i * 8] = *(const f16x8*)(W2Tg + (size_t)(nb * 16 + mm) * CH + kk * 32 + qq * 8);
    }
    __syncthreads();

    float biasA = b2[lane], biasB = b2[lane + 64];
    const f16x8 z8 = {};

    int npairs = (n_nodes + 1) >> 1;
    int pairIdx = blockIdx.x * 4 + w;
    if (pairIdx >= npairs) return;

    // wave-uniform CSR meta -> SGPRs
    auto meta = [&](int p, int& A, int& B, int& C) {
        int pc = min(p, npairs - 1);
        int n0 = 2 * pc;
        int A_ = row_ptr[n0], B_ = row_ptr[n0 + 1];
        int C_ = (n0 + 1 < n_nodes) ? row_ptr[n0 + 2] : B_;
        A = __builtin_amdgcn_readfirstlane(A_);
        B = __builtin_amdgcn_readfirstlane(B_);
        C = __builtin_amdgcn_readfirstlane(C_);
    };
    // clamped sed fetch: rows beyond [lo,hi) duplicate the last valid edge (max-safe)
    auto sidx = [&](int lo, int hi, int off) {
        int ix = min(lo + off, hi - 1);
        ix = max(ix, 0);
        return sed[ix];
    };
    auto loadQs = [&](int idx, f16x8* qs) {
        const f16* qrow = Q + (size_t)idx * CH;
#pragma unroll
        for (int kk = 0; kk < 4; ++kk) qs[kk] = *(const f16x8*)(qrow + kk * 32 + q * 8);
    };
    auto mkAf = [&](const f16x8* pf, const f16x8* qs, f16x8* af) {
#pragma unroll
        for (int kk = 0; kk < 4; ++kk) af[kk] = __builtin_elementwise_max(pf[kk] + qs[kk], z8);
    };
    // one shared-B tile: 32 LDS reads feed 64 MFMAs (2 nodes)
    auto tilePair = [&](const f16x8* af0, const f16x8* af1, float* rmax0, float* rmax1) {
        unsigned wo = 0;
        asm volatile("" : "+v"(wo));              // per-call opacity: no cross-tile hoist of LDS reads
        const f16* wb = w2lds + wo + (size_t)lane * 8;
#pragma unroll
        for (int nb = 0; nb < 8; ++nb) {
            f32x4 a0 = {0.f, 0.f, 0.f, 0.f}, a1 = {0.f, 0.f, 0.f, 0.f};
#pragma unroll
            for (int kk = 0; kk < 4; ++kk) {
                f16x8 bq = *(const f16x8*)(wb + (nb * 4 + kk) * 512);
                a0 = mfma16(af0[kk], bq, a0);
                a1 = mfma16(af1[kk], bq, a1);
            }
            rmax0[nb] = fmaxf(fmaxf(fmaxf(a0[0], a0[1]), fmaxf(a0[2], a0[3])), rmax0[nb]);
            rmax1[nb] = fmaxf(fmaxf(fmaxf(a1[0], a1[1]), fmaxf(a1[2], a1[3])), rmax1[nb]);
        }
    };
    auto reduceStore = [&](int node, int deg, float* rmax) {
        float o0 = 0.f, o1 = 0.f;
        if (deg > 0) {
#pragma unroll
            for (int nb = 0; nb < 8; ++nb) {
                float v = rmax[nb];
                v = fmaxf(v, __shfl_xor(v, 16));
                v = fmaxf(v, __shfl_xor(v, 32));
                rmax[nb] = v;
            }
            float vA = (q & 2) ? ((q & 1) ? rmax[3] : rmax[2]) : ((q & 1) ? rmax[1] : rmax[0]);
            float vB = (q & 2) ? ((q & 1) ? rmax[7] : rmax[6]) : ((q & 1) ? rmax[5] : rmax[4]);
            o0 = vA + biasA;
            o1 = vB + biasB;
            if (flags & 1) { o0 = fmaxf(o0, 0.f); o1 = fmaxf(o1, 0.f); }
        }
        if (flags & 2) {
            float* orow = final_out + (size_t)node * CH;
            orow[lane] = o0; orow[lane + 64] = o1;
        } else {
            f16* orow = act_out + (size_t)node * CH;
            orow[lane] = (f16)o0; orow[lane + 64] = (f16)o1;
        }
    };

    // ---- prologue: meta for cur+next pair, sed idx for cur+next (tiles 0,1) ----
    int a, b, c, aN, bN, cN;
    meta(pairIdx, a, b, c);
    meta(pairIdx + nwv, aN, bN, cN);
    int i00 = sidx(a, b, m),  i01 = sidx(a, b, 16 + m);
    int i10 = sidx(b, c, m),  i11 = sidx(b, c, 16 + m);
    int j00 = sidx(aN, bN, m), j01 = sidx(aN, bN, 16 + m);
    int j10 = sidx(bN, cN, m), j11 = sidx(bN, cN, 16 + m);

    while (true) {
        int n0 = 2 * pairIdx;
        int n1c = min(n0 + 1, n_nodes - 1);

        // top: issue tile0 qs + P rows + (if needed) tile1 qs; then meta 2 pairs ahead
        f16x8 pf0[4], pf1[4], qsA[4], qsB[4];
        loadQs(i00, qsA);
        loadQs(i10, qsB);
#pragma unroll
        for (int kk = 0; kk < 4; ++kk) {
            pf0[kk] = *(const f16x8*)(P + (size_t)n0 * CH + kk * 32 + q * 8);
            pf1[kk] = *(const f16x8*)(P + (size_t)n1c * CH + kk * 32 + q * 8);
        }
        bool t2 = (b - a > 16) || (c - b > 16);    // wave-uniform
        f16x8 qsA2[4], qsB2[4];
        if (t2) { loadQs(i01, qsA2); loadQs(i11, qsB2); }
        int aNN, bNN, cNN;
        meta(pairIdx + 2 * nwv, aNN, bNN, cNN);

        float rmax0[8], rmax1[8];
#pragma unroll
        for (int nb = 0; nb < 8; ++nb) { rmax0[nb] = -3.4e38f; rmax1[nb] = -3.4e38f; }

        f16x8 af0[4], af1[4];
        mkAf(pf0, qsA, af0);
        mkAf(pf1, qsB, af1);
        tilePair(af0, af1, rmax0, rmax1);
        if (t2) {
            mkAf(pf0, qsA2, af0);
            mkAf(pf1, qsB2, af1);
            tilePair(af0, af1, rmax0, rmax1);
        }
        int T = max((b - a + 15) >> 4, (c - b + 15) >> 4);
        for (int j = 2; j < T; ++j) {              // deg>32: rare serial tail
            int s0 = sidx(a, b, 16 * j + m);
            int s1 = sidx(b, c, 16 * j + m);
            loadQs(s0, qsA);
            loadQs(s1, qsB);
            mkAf(pf0, qsA, af0);
            mkAf(pf1, qsB, af1);
            tilePair(af0, af1, rmax0, rmax1);
        }

        reduceStore(n0, b - a, rmax0);
        if (n0 + 1 < n_nodes) reduceStore(n0 + 1, c - b, rmax1);

        pairIdx += nwv;
        if (pairIdx >= npairs) break;

        // rotate pipeline
        a = aN; b = bN; c = cN;
        aN = aNN; bN = bNN; cN = cNN;
        i00 = j00; i01 = j01; i10 = j10; i11 = j11;
        j00 = sidx(aN, bN, m);  j01 = sidx(aN, bN, 16 + m);
        j10 = sidx(bN, cN, m);  j11 = sidx(bN, cN, 16 + m);
    }
}

extern "C" void kernel_launch(void* const* d_in, const int* in_sizes, int n_in,
                              void* d_out, int out_size, void* d_ws, size_t ws_size,
                              hipStream_t stream) {
    const float* x = (const float*)d_in[0];
    const int* ei  = (const int*)d_in[1];
    int E = in_sizes[1] / 2;
    int N = in_sizes[0] / CH;
    const int* esrc = ei;
    const int* edst = ei + E;

    const float* W1[3] = {(const float*)d_in[2], (const float*)d_in[6],  (const float*)d_in[10]};
    const float* B1[3] = {(const float*)d_in[3], (const float*)d_in[7],  (const float*)d_in[11]};
    const float* W2[3] = {(const float*)d_in[4], (const float*)d_in[8],  (const float*)d_in[12]};
    const float* B2[3] = {(const float*)d_in[5], (const float*)d_in[9],  (const float*)d_in[13]};

    char* base = (char*)d_ws;
    size_t off = 0;
    auto alloc = [&](size_t bytes) -> void* {
        void* p = base + off;
        off = (off + bytes + 255) & ~(size_t)255;
        return p;
    };
    int* counts    = (int*)alloc(sizeof(int) * (size_t)(N + 256));
    size_t zero_bytes = off;                       // counts must start at 0
    int* erank     = (int*)alloc(sizeof(int) * (size_t)E);
    int* row_ptr   = (int*)alloc(sizeof(int) * (size_t)(N + 1));
    int* blockSums = (int*)alloc(sizeof(int) * 256);
    int* blockOff  = (int*)alloc(sizeof(int) * 256);
    int* sed       = (int*)alloc(sizeof(int) * (size_t)E);
    f16* act       = (f16*)alloc(sizeof(f16) * (size_t)N * CH);
    f16* Pb        = (f16*)alloc(sizeof(f16) * (size_t)N * CH);
    f16* Qb        = (f16*)alloc(sizeof(f16) * (size_t)N * CH);
    f16* WcT       = (f16*)alloc(sizeof(f16) * 3 * 256 * CH);
    f16* W2T       = (f16*)alloc(sizeof(f16) * 3 * CH * CH);

    hipMemsetAsync(d_ws, 0, zero_bytes, stream);

    int gE = (E + 255) / 256;
    int gN = (N + 255) / 256;
    int total4 = N * CH / 4;
    int gCvt = (total4 + 255) / 256;
    // fused: hist(+rank) + 3x prep + cvt
    k_front<<<gE + 576 + gCvt, 256, 0, stream>>>(edst, counts, erank, E,
                                                 W1[0], W2[0], W1[1], W2[1], W1[2], W2[2],
                                                 WcT, W2T, x, act, total4, gE);
    k_scan1<<<gN, 256, 0, stream>>>(counts, row_ptr, blockSums, N);
    k_scan2<<<1, 256, 0, stream>>>(blockSums, blockOff, gN);
    k_scan3<<<gN, 256, 0, stream>>>(row_ptr, blockOff, N);
    k_scatter<<<gE, 256, 0, stream>>>(esrc, edst, row_ptr, erank, sed, E);

    int npairs = (N + 1) / 2;
    int gNode = 768;                               // 3 blocks/CU x 256 CU
    if (gNode > (npairs + 3) / 4) gNode = (npairs + 3) / 4;
    int nwv = gNode * 4;                           // pair stride = total waves
    int gG1 = (N + 255) / 256;
    for (int l = 0; l < 3; ++l) {
        k_gemm1<<<gG1, 256, 0, stream>>>(act, WcT + l * 256 * CH, B1[l], Pb, Qb, N);
        int flags = (l < 2) ? 1 : 2;
        k_node<<<gNode, 256, 0, stream>>>(Pb, Qb, W2T + l * CH * CH, B2[l],
                                          row_ptr, sed, act, (float*)d_out, N, flags, nwv);
    }
}

// Round 10
// 542.186 us; speedup vs baseline: 1.0101x; 1.0101x over previous
//
#include <hip/hip_runtime.h>

#define CH 128

typedef _Float16 f16;
typedef _Float16 f16x8 __attribute__((ext_vector_type(8)));
typedef float f32x4 __attribute__((ext_vector_type(4)));

__device__ __forceinline__ f32x4 mfma16(f16x8 a, f16x8 b, f32x4 c) {
    return __builtin_amdgcn_mfma_f32_16x16x32_f16(a, b, c, 0, 0, 0);
}

// ---------------- fused front: hist(+rank) + weight prep (3 layers) + x->f16 cvt ----------------
__global__ __launch_bounds__(256) void k_front(const int* __restrict__ edst, int* __restrict__ counts,
                                               int* __restrict__ erank, int E,
                                               const float* __restrict__ W1a, const float* __restrict__ W2a,
                                               const float* __restrict__ W1b, const float* __restrict__ W2b,
                                               const float* __restrict__ W1c, const float* __restrict__ W2c,
                                               f16* __restrict__ WcT, f16* __restrict__ W2T,
                                               const float* __restrict__ x, f16* __restrict__ act,
                                               int total4, int gHist) {
    int bid = blockIdx.x;
    if (bid < gHist) {
        int e = bid * 256 + threadIdx.x;
        if (e < E) erank[e] = atomicAdd(&counts[edst[e]], 1);   // rank doubles as scatter cursor
    } else if (bid < gHist + 576) {
        int r = bid - gHist;
        int l = r / 192;
        const float* W1 = (l == 0) ? W1a : (l == 1) ? W1b : W1c;
        const float* W2 = (l == 0) ? W2a : (l == 1) ? W2b : W2c;
        f16* wct = WcT + l * 256 * CH;
        f16* w2t = W2T + l * CH * CH;
        int id = (r % 192) * 256 + threadIdx.x;   // 49152 per layer
        if (id < 32768) {
            int n = id >> 7, k = id & 127;
            float v;
            if (n < CH) v = W1[k * CH + n] - W1[(CH + k) * CH + n];
            else        v = W1[(CH + k) * CH + (n - CH)];
            wct[n * CH + k] = (f16)v;
        } else {
            int rr = id - 32768;
            int n = rr >> 7, k = rr & 127;
            w2t[n * CH + k] = (f16)W2[k * CH + n];
        }
    } else {
        int i = (bid - gHist - 576) * 256 + threadIdx.x;
        if (i < total4) {
            float4 v = ((const float4*)x)[i];
            f16 h0 = (f16)v.x, h1 = (f16)v.y, h2 = (f16)v.z, h3 = (f16)v.w;
            short4 s;
            s.x = *(short*)&h0; s.y = *(short*)&h1; s.z = *(short*)&h2; s.w = *(short*)&h3;
            ((short4*)act)[i] = s;
        }
    }
}

// ---------------- CSR scans + scatter ----------------
__global__ __launch_bounds__(256) void k_scan1(const int* __restrict__ counts, int* __restrict__ row_ptr,
                                               int* __restrict__ blockSums, int n) {
    __shared__ int s[256];
    int t = threadIdx.x;
    int i = blockIdx.x * 256 + t;
    s[t] = (i < n) ? counts[i] : 0;
    __syncthreads();
    for (int off = 1; off < 256; off <<= 1) {
        int x = (t >= off) ? s[t - off] : 0;
        __syncthreads();
        s[t] += x;
        __syncthreads();
    }
    if (i < n) row_ptr[i + 1] = s[t];
    if (t == 255) blockSums[blockIdx.x] = s[255];
}

__global__ __launch_bounds__(256) void k_scan2(const int* __restrict__ blockSums, int* __restrict__ blockOff, int nb) {
    __shared__ int s[256];
    int t = threadIdx.x;
    s[t] = (t < nb) ? blockSums[t] : 0;
    __syncthreads();
    for (int off = 1; off < 256; off <<= 1) {
        int x = (t >= off) ? s[t - off] : 0;
        __syncthreads();
        s[t] += x;
        __syncthreads();
    }
    blockOff[t] = (t == 0) ? 0 : s[t - 1];
}

__global__ __launch_bounds__(256) void k_scan3(int* __restrict__ row_ptr, const int* __restrict__ blockOff, int n) {
    int i = blockIdx.x * 256 + threadIdx.x;
    if (i < n) row_ptr[i + 1] += blockOff[blockIdx.x];
    if (blockIdx.x == 0 && threadIdx.x == 0) row_ptr[0] = 0;
}

// atomic-free scatter: pos = row_ptr[dst] + precomputed rank
__global__ __launch_bounds__(256) void k_scatter(const int* __restrict__ src, const int* __restrict__ dst,
                                                 const int* __restrict__ row_ptr, const int* __restrict__ erank,
                                                 int* __restrict__ sed, int E) {
    int e = blockIdx.x * 256 + threadIdx.x;
    if (e < E) {
        int pos = row_ptr[dst[e]] + erank[e];
        sed[pos] = src[e];
    }
}

// ---------------- node GEMM: [P|Q] = act @ WcT^T, P gets +b1. 256 rows/block ----------------
__global__ __launch_bounds__(256) void k_gemm1(const f16* __restrict__ act, const f16* __restrict__ WcT,
                                               const float* __restrict__ b1,
                                               f16* __restrict__ P, f16* __restrict__ Q, int nrows) {
    int t = threadIdx.x;
    int w = t >> 6, lane = t & 63;
    int m = lane & 15, q = lane >> 4;
    int rowbase = blockIdx.x * 256 + w * 64;
    f16x8 a[4][4];   // [row-tile][kk]
#pragma unroll
    for (int rt = 0; rt < 4; ++rt) {
        int rowc = min(rowbase + rt * 16 + m, nrows - 1);
#pragma unroll
        for (int kk = 0; kk < 4; ++kk)
            a[rt][kk] = *(const f16x8*)(act + (size_t)rowc * CH + kk * 32 + q * 8);
    }
#pragma unroll
    for (int nb = 0; nb < 16; ++nb) {
        f16x8 b[4];
#pragma unroll
        for (int kk = 0; kk < 4; ++kk)
            b[kk] = *(const f16x8*)(WcT + (nb * 16 + m) * CH + kk * 32 + q * 8);
        int col = nb * 16 + m;
        float bias = (nb < 8) ? b1[col] : 0.f;
#pragma unroll
        for (int rt = 0; rt < 4; ++rt) {
            f32x4 acc = {0.f, 0.f, 0.f, 0.f};
#pragma unroll
            for (int kk = 0; kk < 4; ++kk) acc = mfma16(a[rt][kk], b[kk], acc);
#pragma unroll
            for (int r = 0; r < 4; ++r) {
                int ro = rowbase + rt * 16 + q * 4 + r;
                if (ro < nrows) {
                    float v = acc[r] + bias;
                    if (nb < 8) P[(size_t)ro * CH + col] = (f16)v;
                    else        Q[(size_t)ro * CH + (col - CH)] = (f16)v;
                }
            }
        }
    }
}

// ---------------- per-pair edge GEMM + register max: 1 wave = 2 consecutive dst nodes ----
// v7 = v6 pairing with liveness fixed (v6 spilled: 170+ live regs > 168 budget,
// WRITE_SIZE 159MB). Changes: (a) in-place A-fragments (relu(p+q) overwrites qs; no
// separate af arrays, -64 live); (b) tile-1 data loaded AFTER tilePair#0 (qs regs
// reused, -32 peak). Peak live ~115 regs. B-fragment LDS reads shared across the
// pair: -40% LDS traffic vs v3 (the measured 2.3GB floor).
// flags: bit0 relu out, bit1 fp32 final out.
__global__ __launch_bounds__(256, 3)
void k_node(const f16* __restrict__ P, const f16* __restrict__ Q,
            const f16* __restrict__ W2Tg, const float* __restrict__ b2,
            const int* __restrict__ row_ptr, const int* __restrict__ sed,
            f16* __restrict__ act_out, float* __restrict__ final_out,
            int n_nodes, int flags, int nwv) {
    // W2^T in fragment order: chunk cid=(nb*4+kk)*64+lane holds the 16B this lane
    // needs for (nb,kk). ds_read_b128 at lane*16 + imm -> lane-contiguous, conflict-free.
    __shared__ __align__(16) f16 w2lds[8 * 4 * 64 * 8];   // 32 KB

    int t = threadIdx.x;
    int w = t >> 6, lane = t & 63;
    int m = lane & 15, q = lane >> 4;

#pragma unroll
    for (int i = t; i < 2048; i += 256) {
        int nb = i >> 8, rem = i & 255, kk = rem >> 6, ln = rem & 63;
        int mm = ln & 15, qq = ln >> 4;
        *(f16x8*)&w2lds[i * 8] = *(const f16x8*)(W2Tg + (size_t)(nb * 16 + mm) * CH + kk * 32 + qq * 8);
    }
    __syncthreads();

    float biasA = b2[lane], biasB = b2[lane + 64];
    const f16x8 z8 = {};

    int npairs = (n_nodes + 1) >> 1;
    int pairIdx = blockIdx.x * 4 + w;
    if (pairIdx >= npairs) return;

    // wave-uniform CSR meta -> SGPRs
    auto meta = [&](int p, int& A, int& B, int& C) {
        int pc = min(p, npairs - 1);
        int n0 = 2 * pc;
        int A_ = row_ptr[n0], B_ = row_ptr[n0 + 1];
        int C_ = (n0 + 1 < n_nodes) ? row_ptr[n0 + 2] : B_;
        A = __builtin_amdgcn_readfirstlane(A_);
        B = __builtin_amdgcn_readfirstlane(B_);
        C = __builtin_amdgcn_readfirstlane(C_);
    };
    // clamped sed fetch: rows beyond [lo,hi) duplicate the last valid edge (max-safe)
    auto sidx = [&](int lo, int hi, int off) {
        int ix = min(lo + off, hi - 1);
        ix = max(ix, 0);
        return sed[ix];
    };
    auto loadQs = [&](int idx, f16x8* qs) {
        const f16* qrow = Q + (size_t)idx * CH;
#pragma unroll
        for (int kk = 0; kk < 4; ++kk) qs[kk] = *(const f16x8*)(qrow + kk * 32 + q * 8);
    };
    // in-place A-fragment: qs <- relu(pf + qs)
    auto mkAf = [&](const f16x8* pf, f16x8* qs) {
#pragma unroll
        for (int kk = 0; kk < 4; ++kk) qs[kk] = __builtin_elementwise_max(pf[kk] + qs[kk], z8);
    };
    // one shared-B tile: 32 LDS reads feed 64 MFMAs (2 nodes); af passed in qs arrays
    auto tilePair = [&](const f16x8* af0, const f16x8* af1, float* rmax0, float* rmax1) {
        unsigned wo = 0;
        asm volatile("" : "+v"(wo));              // per-call opacity: no cross-tile hoist of LDS reads
        const f16* wb = w2lds + wo + (size_t)lane * 8;
#pragma unroll
        for (int nb = 0; nb < 8; ++nb) {
            f32x4 a0 = {0.f, 0.f, 0.f, 0.f}, a1 = {0.f, 0.f, 0.f, 0.f};
#pragma unroll
            for (int kk = 0; kk < 4; ++kk) {
                f16x8 bq = *(const f16x8*)(wb + (nb * 4 + kk) * 512);
                a0 = mfma16(af0[kk], bq, a0);
                a1 = mfma16(af1[kk], bq, a1);
            }
            rmax0[nb] = fmaxf(fmaxf(fmaxf(a0[0], a0[1]), fmaxf(a0[2], a0[3])), rmax0[nb]);
            rmax1[nb] = fmaxf(fmaxf(fmaxf(a1[0], a1[1]), fmaxf(a1[2], a1[3])), rmax1[nb]);
        }
    };
    auto reduceStore = [&](int node, int deg, float* rmax) {
        float o0 = 0.f, o1 = 0.f;
        if (deg > 0) {
#pragma unroll
            for (int nb = 0; nb < 8; ++nb) {
                float v = rmax[nb];
                v = fmaxf(v, __shfl_xor(v, 16));
                v = fmaxf(v, __shfl_xor(v, 32));
                rmax[nb] = v;
            }
            float vA = (q & 2) ? ((q & 1) ? rmax[3] : rmax[2]) : ((q & 1) ? rmax[1] : rmax[0]);
            float vB = (q & 2) ? ((q & 1) ? rmax[7] : rmax[6]) : ((q & 1) ? rmax[5] : rmax[4]);
            o0 = vA + biasA;
            o1 = vB + biasB;
            if (flags & 1) { o0 = fmaxf(o0, 0.f); o1 = fmaxf(o1, 0.f); }
        }
        if (flags & 2) {
            float* orow = final_out + (size_t)node * CH;
            orow[lane] = o0; orow[lane + 64] = o1;
        } else {
            f16* orow = act_out + (size_t)node * CH;
            orow[lane] = (f16)o0; orow[lane + 64] = (f16)o1;
        }
    };

    // ---- prologue: meta for cur+next pair, sed idx for cur+next (tiles 0,1) ----
    int a, b, c, aN, bN, cN;
    meta(pairIdx, a, b, c);
    meta(pairIdx + nwv, aN, bN, cN);
    int i00 = sidx(a, b, m),  i01 = sidx(a, b, 16 + m);
    int i10 = sidx(b, c, m),  i11 = sidx(b, c, 16 + m);
    int j00 = sidx(aN, bN, m), j01 = sidx(aN, bN, 16 + m);
    int j10 = sidx(bN, cN, m), j11 = sidx(bN, cN, 16 + m);

    while (true) {
        int n0 = 2 * pairIdx;
        int n1c = min(n0 + 1, n_nodes - 1);

        // top: tile-0 qs + P rows only (minimal live set); meta 2 pairs ahead
        f16x8 pf0[4], pf1[4], qsA[4], qsB[4];
        loadQs(i00, qsA);
        loadQs(i10, qsB);
#pragma unroll
        for (int kk = 0; kk < 4; ++kk) {
            pf0[kk] = *(const f16x8*)(P + (size_t)n0 * CH + kk * 32 + q * 8);
            pf1[kk] = *(const f16x8*)(P + (size_t)n1c * CH + kk * 32 + q * 8);
        }
        int aNN, bNN, cNN;
        meta(pairIdx + 2 * nwv, aNN, bNN, cNN);

        float rmax0[8], rmax1[8];
#pragma unroll
        for (int nb = 0; nb < 8; ++nb) { rmax0[nb] = -3.4e38f; rmax1[nb] = -3.4e38f; }

        mkAf(pf0, qsA);
        mkAf(pf1, qsB);
        tilePair(qsA, qsB, rmax0, rmax1);          // qsA/qsB dead after -> regs reused below

        bool t2 = (b - a > 16) || (c - b > 16);    // wave-uniform
        if (t2) {
            loadQs(i01, qsA);                       // reuse qs registers for tile 1
            loadQs(i11, qsB);
            mkAf(pf0, qsA);
            mkAf(pf1, qsB);
            tilePair(qsA, qsB, rmax0, rmax1);
        }
        int T = max((b - a + 15) >> 4, (c - b + 15) >> 4);
        for (int j = 2; j < T; ++j) {              // deg>32: rare serial tail
            loadQs(sidx(a, b, 16 * j + m), qsA);
            loadQs(sidx(b, c, 16 * j + m), qsB);
            mkAf(pf0, qsA);
            mkAf(pf1, qsB);
            tilePair(qsA, qsB, rmax0, rmax1);
        }

        reduceStore(n0, b - a, rmax0);
        if (n0 + 1 < n_nodes) reduceStore(n0 + 1, c - b, rmax1);

        pairIdx += nwv;
        if (pairIdx >= npairs) break;

        // rotate pipeline
        a = aN; b = bN; c = cN;
        aN = aNN; bN = bNN; cN = cNN;
        i00 = j00; i01 = j01; i10 = j10; i11 = j11;
        j00 = sidx(aN, bN, m);  j01 = sidx(aN, bN, 16 + m);
        j10 = sidx(bN, cN, m);  j11 = sidx(bN, cN, 16 + m);
    }
}

extern "C" void kernel_launch(void* const* d_in, const int* in_sizes, int n_in,
                              void* d_out, int out_size, void* d_ws, size_t ws_size,
                              hipStream_t stream) {
    const float* x = (const float*)d_in[0];
    const int* ei  = (const int*)d_in[1];
    int E = in_sizes[1] / 2;
    int N = in_sizes[0] / CH;
    const int* esrc = ei;
    const int* edst = ei + E;

    const float* W1[3] = {(const float*)d_in[2], (const float*)d_in[6],  (const float*)d_in[10]};
    const float* B1[3] = {(const float*)d_in[3], (const float*)d_in[7],  (const float*)d_in[11]};
    const float* W2[3] = {(const float*)d_in[4], (const float*)d_in[8],  (const float*)d_in[12]};
    const float* B2[3] = {(const float*)d_in[5], (const float*)d_in[9],  (const float*)d_in[13]};

    char* base = (char*)d_ws;
    size_t off = 0;
    auto alloc = [&](size_t bytes) -> void* {
        void* p = base + off;
        off = (off + bytes + 255) & ~(size_t)255;
        return p;
    };
    int* counts    = (int*)alloc(sizeof(int) * (size_t)(N + 256));
    size_t zero_bytes = off;                       // counts must start at 0
    int* erank     = (int*)alloc(sizeof(int) * (size_t)E);
    int* row_ptr   = (int*)alloc(sizeof(int) * (size_t)(N + 1));
    int* blockSums = (int*)alloc(sizeof(int) * 256);
    int* blockOff  = (int*)alloc(sizeof(int) * 256);
    int* sed       = (int*)alloc(sizeof(int) * (size_t)E);
    f16* act       = (f16*)alloc(sizeof(f16) * (size_t)N * CH);
    f16* Pb        = (f16*)alloc(sizeof(f16) * (size_t)N * CH);
    f16* Qb        = (f16*)alloc(sizeof(f16) * (size_t)N * CH);
    f16* WcT       = (f16*)alloc(sizeof(f16) * 3 * 256 * CH);
    f16* W2T       = (f16*)alloc(sizeof(f16) * 3 * CH * CH);

    hipMemsetAsync(d_ws, 0, zero_bytes, stream);

    int gE = (E + 255) / 256;
    int gN = (N + 255) / 256;
    int total4 = N * CH / 4;
    int gCvt = (total4 + 255) / 256;
    // fused: hist(+rank) + 3x prep + cvt
    k_front<<<gE + 576 + gCvt, 256, 0, stream>>>(edst, counts, erank, E,
                                                 W1[0], W2[0], W1[1], W2[1], W1[2], W2[2],
                                                 WcT, W2T, x, act, total4, gE);
    k_scan1<<<gN, 256, 0, stream>>>(counts, row_ptr, blockSums, N);
    k_scan2<<<1, 256, 0, stream>>>(blockSums, blockOff, gN);
    k_scan3<<<gN, 256, 0, stream>>>(row_ptr, blockOff, N);
    k_scatter<<<gE, 256, 0, stream>>>(esrc, edst, row_ptr, erank, sed, E);

    int npairs = (N + 1) / 2;
    int gNode = 768;                               // 3 blocks/CU x 256 CU
    if (gNode > (npairs + 3) / 4) gNode = (npairs + 3) / 4;
    int nwv = gNode * 4;                           // pair stride = total waves
    int gG1 = (N + 255) / 256;
    for (int l = 0; l < 3; ++l) {
        k_gemm1<<<gG1, 256, 0, stream>>>(act, WcT + l * 256 * CH, B1[l], Pb, Qb, N);
        int flags = (l < 2) ? 1 : 2;
        k_node<<<gNode, 256, 0, stream>>>(Pb, Qb, W2T + l * CH * CH, B2[l],
                                          row_ptr, sed, act, (float*)d_out, N, flags, nwv);
    }
}

// Round 11
// 388.245 us; speedup vs baseline: 1.4106x; 1.3965x over previous
//
#include <hip/hip_runtime.h>

#define CH 128

typedef _Float16 f16;
typedef _Float16 f16x8 __attribute__((ext_vector_type(8)));
typedef float f32x4 __attribute__((ext_vector_type(4)));

__device__ __forceinline__ f32x4 mfma16(f16x8 a, f16x8 b, f32x4 c) {
    return __builtin_amdgcn_mfma_f32_16x16x32_f16(a, b, c, 0, 0, 0);
}

// ---------------- fused front: hist(+rank) + weight prep (3 layers) + x->f16 cvt ----------------
__global__ __launch_bounds__(256) void k_front(const int* __restrict__ edst, int* __restrict__ counts,
                                               int* __restrict__ erank, int E,
                                               const float* __restrict__ W1a, const float* __restrict__ W2a,
                                               const float* __restrict__ W1b, const float* __restrict__ W2b,
                                               const float* __restrict__ W1c, const float* __restrict__ W2c,
                                               f16* __restrict__ WcT, f16* __restrict__ W2T,
                                               const float* __restrict__ x, f16* __restrict__ act,
                                               int total4, int gHist) {
    int bid = blockIdx.x;
    if (bid < gHist) {
        int e = bid * 256 + threadIdx.x;
        if (e < E) erank[e] = atomicAdd(&counts[edst[e]], 1);   // rank doubles as scatter cursor
    } else if (bid < gHist + 576) {
        int r = bid - gHist;
        int l = r / 192;
        const float* W1 = (l == 0) ? W1a : (l == 1) ? W1b : W1c;
        const float* W2 = (l == 0) ? W2a : (l == 1) ? W2b : W2c;
        f16* wct = WcT + l * 256 * CH;
        f16* w2t = W2T + l * CH * CH;
        int id = (r % 192) * 256 + threadIdx.x;   // 49152 per layer
        if (id < 32768) {
            int n = id >> 7, k = id & 127;
            float v;
            if (n < CH) v = W1[k * CH + n] - W1[(CH + k) * CH + n];
            else        v = W1[(CH + k) * CH + (n - CH)];
            wct[n * CH + k] = (f16)v;
        } else {
            int rr = id - 32768;
            int n = rr >> 7, k = rr & 127;
            w2t[n * CH + k] = (f16)W2[k * CH + n];
        }
    } else {
        int i = (bid - gHist - 576) * 256 + threadIdx.x;
        if (i < total4) {
            float4 v = ((const float4*)x)[i];
            f16 h0 = (f16)v.x, h1 = (f16)v.y, h2 = (f16)v.z, h3 = (f16)v.w;
            short4 s;
            s.x = *(short*)&h0; s.y = *(short*)&h1; s.z = *(short*)&h2; s.w = *(short*)&h3;
            ((short4*)act)[i] = s;
        }
    }
}

// ---------------- CSR scans + scatter ----------------
__global__ __launch_bounds__(256) void k_scan1(const int* __restrict__ counts, int* __restrict__ row_ptr,
                                               int* __restrict__ blockSums, int n) {
    __shared__ int s[256];
    int t = threadIdx.x;
    int i = blockIdx.x * 256 + t;
    s[t] = (i < n) ? counts[i] : 0;
    __syncthreads();
    for (int off = 1; off < 256; off <<= 1) {
        int x = (t >= off) ? s[t - off] : 0;
        __syncthreads();
        s[t] += x;
        __syncthreads();
    }
    if (i < n) row_ptr[i + 1] = s[t];
    if (t == 255) blockSums[blockIdx.x] = s[255];
}

__global__ __launch_bounds__(256) void k_scan2(const int* __restrict__ blockSums, int* __restrict__ blockOff, int nb) {
    __shared__ int s[256];
    int t = threadIdx.x;
    s[t] = (t < nb) ? blockSums[t] : 0;
    __syncthreads();
    for (int off = 1; off < 256; off <<= 1) {
        int x = (t >= off) ? s[t - off] : 0;
        __syncthreads();
        s[t] += x;
        __syncthreads();
    }
    blockOff[t] = (t == 0) ? 0 : s[t - 1];
}

__global__ __launch_bounds__(256) void k_scan3(int* __restrict__ row_ptr, const int* __restrict__ blockOff, int n) {
    int i = blockIdx.x * 256 + threadIdx.x;
    if (i < n) row_ptr[i + 1] += blockOff[blockIdx.x];
    if (blockIdx.x == 0 && threadIdx.x == 0) row_ptr[0] = 0;
}

// atomic-free scatter: pos = row_ptr[dst] + precomputed rank
__global__ __launch_bounds__(256) void k_scatter(const int* __restrict__ src, const int* __restrict__ dst,
                                                 const int* __restrict__ row_ptr, const int* __restrict__ erank,
                                                 int* __restrict__ sed, int E) {
    int e = blockIdx.x * 256 + threadIdx.x;
    if (e < E) {
        int pos = row_ptr[dst[e]] + erank[e];
        sed[pos] = src[e];
    }
}

// ---------------- node GEMM: [P|Q] = act @ WcT^T, P gets +b1. 256 rows/block ----------------
__global__ __launch_bounds__(256) void k_gemm1(const f16* __restrict__ act, const f16* __restrict__ WcT,
                                               const float* __restrict__ b1,
                                               f16* __restrict__ P, f16* __restrict__ Q, int nrows) {
    int t = threadIdx.x;
    int w = t >> 6, lane = t & 63;
    int m = lane & 15, q = lane >> 4;
    int rowbase = blockIdx.x * 256 + w * 64;
    f16x8 a[4][4];   // [row-tile][kk]
#pragma unroll
    for (int rt = 0; rt < 4; ++rt) {
        int rowc = min(rowbase + rt * 16 + m, nrows - 1);
#pragma unroll
        for (int kk = 0; kk < 4; ++kk)
            a[rt][kk] = *(const f16x8*)(act + (size_t)rowc * CH + kk * 32 + q * 8);
    }
#pragma unroll
    for (int nb = 0; nb < 16; ++nb) {
        f16x8 b[4];
#pragma unroll
        for (int kk = 0; kk < 4; ++kk)
            b[kk] = *(const f16x8*)(WcT + (nb * 16 + m) * CH + kk * 32 + q * 8);
        int col = nb * 16 + m;
        float bias = (nb < 8) ? b1[col] : 0.f;
#pragma unroll
        for (int rt = 0; rt < 4; ++rt) {
            f32x4 acc = {0.f, 0.f, 0.f, 0.f};
#pragma unroll
            for (int kk = 0; kk < 4; ++kk) acc = mfma16(a[rt][kk], b[kk], acc);
#pragma unroll
            for (int r = 0; r < 4; ++r) {
                int ro = rowbase + rt * 16 + q * 4 + r;
                if (ro < nrows) {
                    float v = acc[r] + bias;
                    if (nb < 8) P[(size_t)ro * CH + col] = (f16)v;
                    else        Q[(size_t)ro * CH + (col - CH)] = (f16)v;
                }
            }
        }
    }
}

// ---------------- per-node edge GEMM + register max: 1 wave = 1 dst node ----------------
// v8 = v3 (round-5 proven: 73.8us, no spill) with ONE change: when deg>16, the two
// tiles' B-passes fuse into tile2 — each W2-fragment ds_read feeds 2 MFMAs (tiles of
// the SAME node share B and rmax). B LDS passes/node: 1.46 -> 1.03 (-29% of the
// measured-dominant 2.3GB LDS traffic). nb-outer/kk-inner cuts acc regs 32->8 vs v3.
// Cross-node pair structure abandoned: 3 spill strikes (v6/v7 WRITE_SIZE 159/129MB).
// flags: bit0 relu out, bit1 fp32 final out.
__global__ __launch_bounds__(256, 3)
void k_node(const f16* __restrict__ P, const f16* __restrict__ Q,
            const f16* __restrict__ W2Tg, const float* __restrict__ b2,
            const int* __restrict__ row_ptr, const int* __restrict__ sed,
            f16* __restrict__ act_out, float* __restrict__ final_out,
            int n_nodes, int flags, int nwv) {
    // W2^T in fragment order: chunk cid=(nb*4+kk)*64+lane holds the 16B this lane
    // needs for (nb,kk). ds_read_b128 at lane*16 + imm -> lane-contiguous, conflict-free.
    __shared__ __align__(16) f16 w2lds[8 * 4 * 64 * 8];   // 32 KB

    int t = threadIdx.x;
    int w = t >> 6, lane = t & 63;
    int m = lane & 15, q = lane >> 4;

#pragma unroll
    for (int i = t; i < 2048; i += 256) {
        int nb = i >> 8, rem = i & 255, kk = rem >> 6, ln = rem & 63;
        int mm = ln & 15, qq = ln >> 4;
        *(f16x8*)&w2lds[i * 8] = *(const f16x8*)(W2Tg + (size_t)(nb * 16 + mm) * CH + kk * 32 + qq * 8);
    }
    __syncthreads();

    float biasA = b2[lane], biasB = b2[lane + 64];
    const f16x8 z8 = {};
    const f32x4 z4 = {0.f, 0.f, 0.f, 0.f};

    // in-place A-fragment: qs <- relu(pf + qs)  (pf untouched)
    auto mkAf = [&](const f16x8* pf, f16x8* qs) {
#pragma unroll
        for (int kk = 0; kk < 4; ++kk) qs[kk] = __builtin_elementwise_max(pf[kk] + qs[kk], z8);
    };
    // single-tile B pass (af precomputed)
    auto tile1 = [&](const f16x8* af, float* rmax) {
        unsigned wo = 0;
        asm volatile("" : "+v"(wo));              // per-call opacity: no LICM hoist of LDS reads
        const f16* wb = w2lds + wo + (size_t)lane * 8;
#pragma unroll
        for (int nb = 0; nb < 8; ++nb) {
            f32x4 a0 = z4;
#pragma unroll
            for (int kk = 0; kk < 4; ++kk) {
                f16x8 bq = *(const f16x8*)(wb + (nb * 4 + kk) * 512);
                a0 = mfma16(af[kk], bq, a0);
            }
            rmax[nb] = fmaxf(fmaxf(fmaxf(a0[0], a0[1]), fmaxf(a0[2], a0[3])), rmax[nb]);
        }
    };
    // dual-tile B pass: each bq read feeds both tiles (same node -> shared rmax)
    auto tile2 = [&](const f16x8* af0, const f16x8* af1, float* rmax) {
        unsigned wo = 0;
        asm volatile("" : "+v"(wo));
        const f16* wb = w2lds + wo + (size_t)lane * 8;
#pragma unroll
        for (int nb = 0; nb < 8; ++nb) {
            f32x4 a0 = z4, a1 = z4;
#pragma unroll
            for (int kk = 0; kk < 4; ++kk) {
                f16x8 bq = *(const f16x8*)(wb + (nb * 4 + kk) * 512);
                a0 = mfma16(af0[kk], bq, a0);
                a1 = mfma16(af1[kk], bq, a1);
            }
            a0 = __builtin_elementwise_max(a0, a1);
            rmax[nb] = fmaxf(fmaxf(fmaxf(a0[0], a0[1]), fmaxf(a0[2], a0[3])), rmax[nb]);
        }
    };

    int nA = blockIdx.x * 4 + w;
    if (nA >= n_nodes) return;
    int nmax = n_nodes - 1;

    // ---- prologue: fill 4-stage pipeline (identical to v3) ----
    int rsA = row_ptr[nA], reA = row_ptr[nA + 1];
    int nB = nA + nwv; int nBc = min(nB, nmax);
    int rsB = row_ptr[nBc], reB = row_ptr[nBc + 1];
    int nC = nB + nwv; int nCc = min(nC, nmax);
    int rsC = row_ptr[nCc], reC = row_ptr[nCc + 1];

    int lA = (reA > rsA) ? reA - 1 : 0;
    int idx0A = sed[min(rsA + m, lA)];
    int idx1A = sed[min(rsA + 16 + m, lA)];
    int lB = (reB > rsB) ? reB - 1 : 0;
    int idx0B = sed[min(rsB + m, lB)];
    int idx1B = sed[min(rsB + 16 + m, lB)];

    f16x8 pfA[4], qs0A[4];
#pragma unroll
    for (int kk = 0; kk < 4; ++kk) {
        pfA[kk]  = *(const f16x8*)(P + (size_t)nA * CH + kk * 32 + q * 8);
        qs0A[kk] = *(const f16x8*)(Q + (size_t)idx0A * CH + kk * 32 + q * 8);
    }

    while (true) {
        // ---- top: batch-issue all future loads (max bytes in flight) ----
        f16x8 qs1A[4] = {};                       // tile-1 rows for current node (idx1A: 2 iters old)
        if (reA - rsA > 16) {
#pragma unroll
            for (int kk = 0; kk < 4; ++kk)
                qs1A[kk] = *(const f16x8*)(Q + (size_t)idx1A * CH + kk * 32 + q * 8);
        }
        f16x8 qs0B[4], pfB[4];                    // next node's tile-0 + P row
#pragma unroll
        for (int kk = 0; kk < 4; ++kk) {
            qs0B[kk] = *(const f16x8*)(Q + (size_t)idx0B * CH + kk * 32 + q * 8);
            pfB[kk]  = *(const f16x8*)(P + (size_t)nBc * CH + kk * 32 + q * 8);
        }
        int lC = (reC > rsC) ? reC - 1 : 0;       // idx for node 2 ahead
        int idx0C = sed[min(rsC + m, lC)];
        int idx1C = sed[min(rsC + 16 + m, lC)];
        int nD = nC + nwv; int nDc = min(nD, nmax);
        int rsD = row_ptr[nDc], reD = row_ptr[nDc + 1];

        // ---- compute node nA ----
        float o0 = 0.f, o1 = 0.f;
        if (reA > rsA) {
            float rmax[8];
#pragma unroll
            for (int nb = 0; nb < 8; ++nb) rmax[nb] = -3.4e38f;
            mkAf(pfA, qs0A);
            if (reA - rsA > 16) {
                mkAf(pfA, qs1A);
                tile2(qs0A, qs1A, rmax);          // fused B pass for tiles 0+1
            } else {
                tile1(qs0A, rmax);
            }
            for (int tb = rsA + 32; tb < reA; tb += 16) {   // deg>32: rare serial tail
                int s2 = sed[min(tb + m, reA - 1)];
                f16x8 qx[4];
#pragma unroll
                for (int kk = 0; kk < 4; ++kk)
                    qx[kk] = *(const f16x8*)(Q + (size_t)s2 * CH + kk * 32 + q * 8);
                mkAf(pfA, qx);
                tile1(qx, rmax);
            }
            // cross-q reduce: lanes l, l^16, l^32, l^48 hold the 4 row-groups of each col
#pragma unroll
            for (int nb = 0; nb < 8; ++nb) {
                float v = rmax[nb];
                v = fmaxf(v, __shfl_xor(v, 16));
                v = fmaxf(v, __shfl_xor(v, 32));
                rmax[nb] = v;
            }
            float vA = (q & 2) ? ((q & 1) ? rmax[3] : rmax[2]) : ((q & 1) ? rmax[1] : rmax[0]);
            float vB = (q & 2) ? ((q & 1) ? rmax[7] : rmax[6]) : ((q & 1) ? rmax[5] : rmax[4]);
            o0 = vA + biasA;
            o1 = vB + biasB;
            if (flags & 1) { o0 = fmaxf(o0, 0.f); o1 = fmaxf(o1, 0.f); }
        }
        if (flags & 2) {
            float* orow = final_out + (size_t)nA * CH;
            orow[lane] = o0; orow[lane + 64] = o1;
        } else {
            f16* orow = act_out + (size_t)nA * CH;
            orow[lane] = (f16)o0; orow[lane + 64] = (f16)o1;
        }

        if (nB >= n_nodes) break;

        // ---- rotate pipeline ----
        nA = nB; rsA = rsB; reA = reB; idx1A = idx1B;
#pragma unroll
        for (int kk = 0; kk < 4; ++kk) { qs0A[kk] = qs0B[kk]; pfA[kk] = pfB[kk]; }
        idx0B = idx0C; idx1B = idx1C;
        nB = nC; nBc = nCc; rsB = rsC; reB = reC;
        nC = nD; nCc = nDc; rsC = rsD; reC = reD;
    }
}

extern "C" void kernel_launch(void* const* d_in, const int* in_sizes, int n_in,
                              void* d_out, int out_size, void* d_ws, size_t ws_size,
                              hipStream_t stream) {
    const float* x = (const float*)d_in[0];
    const int* ei  = (const int*)d_in[1];
    int E = in_sizes[1] / 2;
    int N = in_sizes[0] / CH;
    const int* esrc = ei;
    const int* edst = ei + E;

    const float* W1[3] = {(const float*)d_in[2], (const float*)d_in[6],  (const float*)d_in[10]};
    const float* B1[3] = {(const float*)d_in[3], (const float*)d_in[7],  (const float*)d_in[11]};
    const float* W2[3] = {(const float*)d_in[4], (const float*)d_in[8],  (const float*)d_in[12]};
    const float* B2[3] = {(const float*)d_in[5], (const float*)d_in[9],  (const float*)d_in[13]};

    char* base = (char*)d_ws;
    size_t off = 0;
    auto alloc = [&](size_t bytes) -> void* {
        void* p = base + off;
        off = (off + bytes + 255) & ~(size_t)255;
        return p;
    };
    int* counts    = (int*)alloc(sizeof(int) * (size_t)(N + 256));
    size_t zero_bytes = off;                       // counts must start at 0
    int* erank     = (int*)alloc(sizeof(int) * (size_t)E);
    int* row_ptr   = (int*)alloc(sizeof(int) * (size_t)(N + 1));
    int* blockSums = (int*)alloc(sizeof(int) * 256);
    int* blockOff  = (int*)alloc(sizeof(int) * 256);
    int* sed       = (int*)alloc(sizeof(int) * (size_t)E);
    f16* act       = (f16*)alloc(sizeof(f16) * (size_t)N * CH);
    f16* Pb        = (f16*)alloc(sizeof(f16) * (size_t)N * CH);
    f16* Qb        = (f16*)alloc(sizeof(f16) * (size_t)N * CH);
    f16* WcT       = (f16*)alloc(sizeof(f16) * 3 * 256 * CH);
    f16* W2T       = (f16*)alloc(sizeof(f16) * 3 * CH * CH);

    hipMemsetAsync(d_ws, 0, zero_bytes, stream);

    int gE = (E + 255) / 256;
    int gN = (N + 255) / 256;
    int total4 = N * CH / 4;
    int gCvt = (total4 + 255) / 256;
    // fused: hist(+rank) + 3x prep + cvt
    k_front<<<gE + 576 + gCvt, 256, 0, stream>>>(edst, counts, erank, E,
                                                 W1[0], W2[0], W1[1], W2[1], W1[2], W2[2],
                                                 WcT, W2T, x, act, total4, gE);
    k_scan1<<<gN, 256, 0, stream>>>(counts, row_ptr, blockSums, N);
    k_scan2<<<1, 256, 0, stream>>>(blockSums, blockOff, gN);
    k_scan3<<<gN, 256, 0, stream>>>(row_ptr, blockOff, N);
    k_scatter<<<gE, 256, 0, stream>>>(esrc, edst, row_ptr, erank, sed, E);

    int gNode = 768;                               // 3 blocks/CU x 256 CU
    if (gNode > (N + 3) / 4) gNode = (N + 3) / 4;
    int nwv = gNode * 4;
    int gG1 = (N + 255) / 256;
    for (int l = 0; l < 3; ++l) {
        k_gemm1<<<gG1, 256, 0, stream>>>(act, WcT + l * 256 * CH, B1[l], Pb, Qb, N);
        int flags = (l < 2) ? 1 : 2;
        k_node<<<gNode, 256, 0, stream>>>(Pb, Qb, W2T + l * CH * CH, B2[l],
                                          row_ptr, sed, act, (float*)d_out, N, flags, nwv);
    }
}